// Round 4
// baseline (230.091 us; speedup 1.0000x reference)
//
#include <hip/hip_runtime.h>

#define HW 256
#define BATCH 8
#define C 64
#define HO 244
#define NPAD 192
#define KTOT 576

typedef __bf16 bf16x8 __attribute__((ext_vector_type(8)));
typedef float f32x16 __attribute__((ext_vector_type(16)));
typedef float f32x4 __attribute__((ext_vector_type(4)));
typedef float f32x2 __attribute__((ext_vector_type(2)));
typedef unsigned short us8 __attribute__((ext_vector_type(8)));

// native RNE float->bf16 (v_cvt_pk_bf16_f32 capable)
__device__ inline unsigned short fbf(float f) {
    return __builtin_bit_cast(unsigned short, (__bf16)f);
}

__device__ inline float bf2f(unsigned short s) {
    union { unsigned int u; float f; } c;
    c.u = ((unsigned int)s) << 16;
    return c.f;
}

// 32-lane butterfly step on the VALU (no LDS pipe): v += dpp_move(v, CTRL)
template <int CTRL>
__device__ inline float dpp_add(float v) {
    int s = __builtin_bit_cast(int, v);
    int m = __builtin_amdgcn_update_dpp(s, s, CTRL, 0xF, 0xF, true);
    return v + __builtin_bit_cast(float, m);
}

// ---- merged W2+W3 repack, fragment-coalesced: [((kstep*2+khalf)*N + n)*8 + e] ----
__global__ __launch_bounds__(256) void repack_w_kernel(
    const float* __restrict__ W2, const float* __restrict__ W3,
    unsigned short* __restrict__ B2g, unsigned short* __restrict__ B3g)
{
    int idx = blockIdx.x * 256 + threadIdx.x;
    if (idx < 36 * 2 * C * 8) {
        int e = idx & 7;
        int r = idx >> 3;
        int n = r & 63;
        int s = r >> 6;
        int khalf = s & 1;
        int kstep = s >> 1;
        int chunk = kstep >> 2, ks = kstep & 3;
        int ci = ks * 16 + khalf * 8 + e;
        B2g[idx] = fbf(W2[((size_t)n * C + ci) * 9 + chunk]);
    } else {
        int j = idx - 36 * 2 * C * 8;
        if (j >= 36 * 2 * NPAD * 8) return;
        int e = j & 7;
        int r = j >> 3;
        int n = r % NPAD;
        int s = r / NPAD;
        int khalf = s & 1;
        int kstep = s >> 1;
        int chunk = kstep >> 2, ks = kstep & 3;
        int ci = ks * 16 + khalf * 8 + e;
        float v = (n < 169) ? W3[((size_t)n * C + ci) * 9 + chunk] : 0.f;
        B3g[j] = fbf(v);
    }
}

// ------- fused conv1+conv2: aligned Ash (stride 72), depth-2 A+B prefetch ------
__global__ __launch_bounds__(256, 3) void conv2_fused_kernel(
    const float* __restrict__ x, const float* __restrict__ W1,
    const float* __restrict__ b1, const unsigned short* __restrict__ W2r,
    const float* __restrict__ b2, unsigned short* __restrict__ h2)
{
    __shared__ unsigned short Ash[396 * 72];   // 57,024 B (stride 144B = 16B-aligned b128)
    __shared__ unsigned short Xsh[8 * 68];     //  1,088 B (bf16)

    const int t = threadIdx.x;
    const int lane = t & 63;
    const int wave = t >> 6;
    const int b  = blockIdx.z;
    const int h0 = blockIdx.y * 4;
    const int w0 = blockIdx.x * 64;

    const int col   = lane & 31;
    const int khalf = lane >> 5;
    const int mrow_base = wave * 64;

    // ---- stage x tile (bf16): rows h0-2..h0+5, cols w0-2..w0+65, zero OOB ----
    const float* __restrict__ xplane = x + ((size_t)b << 16);
#pragma unroll
    for (int it = 0; it < 3; ++it) {
        int li = it * 256 + t;
        if (li < 8 * 68) {
            int rr = li / 68, cc = li - rr * 68;
            int hh = h0 - 2 + rr, ww = w0 - 2 + cc;
            bool ok = (hh >= 0) && (hh < HW) && (ww >= 0) && (ww < HW);
            Xsh[li] = ok ? fbf(xplane[hh * HW + ww]) : (unsigned short)0;
        }
    }

    // this thread's 4 channels as two float2 pairs (packed-math path)
    const int g4 = t & 15;
    f32x2 w01[9], w23[9];
    f32x2 bia01, bia23;
    bia01[0] = b1[g4 * 4 + 0]; bia01[1] = b1[g4 * 4 + 1];
    bia23[0] = b1[g4 * 4 + 2]; bia23[1] = b1[g4 * 4 + 3];
#pragma unroll
    for (int q = 0; q < 9; ++q) {
        w01[q][0] = W1[(g4 * 4 + 0) * 9 + q];
        w01[q][1] = W1[(g4 * 4 + 1) * 9 + q];
        w23[q][0] = W1[(g4 * 4 + 2) * 9 + q];
        w23[q][1] = W1[(g4 * 4 + 3) * 9 + q];
    }

    __syncthreads();   // Xsh ready

    // ---- compute h1 tile (conv1 + ReLU + bf16) into Ash ----
    // unit = 6 consecutive pixels x 4 channels: one us8 LDS read per window row
#pragma unroll
    for (int it = 0; it < 5; ++it) {
        int li = it * 256 + t;                 // li & 15 == g4 (256 % 16 == 0)
        if (li < 1056) {
            int w = li >> 4;                   // 0..65
            int pr = w / 11;                   // Ash row 0..5
            int pc0 = (w - pr * 11) * 6;       // first pixel col (0,6,..,60)
            int hh = h0 - 1 + pr;
            bool okrow = (hh >= 0) && (hh < HW);
            const unsigned short* xb = Xsh + pr * 68 + pc0;

            f32x2 ac01[6], ac23[6];
#pragma unroll
            for (int k2 = 0; k2 < 6; ++k2) { ac01[k2] = bia01; ac23[k2] = bia23; }

#pragma unroll
            for (int i = 0; i < 3; ++i) {
                us8 xw = *(const us8*)(xb + i * 68);
                float xr[8];
#pragma unroll
                for (int e = 0; e < 8; ++e) xr[e] = bf2f(xw[e]);
#pragma unroll
                for (int k2 = 0; k2 < 6; ++k2)
#pragma unroll
                    for (int j = 0; j < 3; ++j) {
                        f32x2 xv2; xv2[0] = xr[k2 + j]; xv2[1] = xr[k2 + j];
                        ac01[k2] += xv2 * w01[i * 3 + j];
                        ac23[k2] += xv2 * w23[i * 3 + j];
                    }
            }

#pragma unroll
            for (int k2 = 0; k2 < 6; ++k2) {
                int ww = w0 - 1 + pc0 + k2;
                bool ok = okrow && (ww >= 0) && (ww < HW);
                unsigned short ov[4];
                if (ok) {
                    ov[0] = fbf(fmaxf(ac01[k2][0], 0.f));
                    ov[1] = fbf(fmaxf(ac01[k2][1], 0.f));
                    ov[2] = fbf(fmaxf(ac23[k2][0], 0.f));
                    ov[3] = fbf(fmaxf(ac23[k2][1], 0.f));
                } else {
                    ov[0] = 0; ov[1] = 0; ov[2] = 0; ov[3] = 0;
                }
                *(uint2*)(Ash + (pr * 66 + pc0 + k2) * 72 + g4 * 4) = *(uint2*)ov;
            }
        }
    }

    // depth-2 B pipeline: bcur = kstep, bnx = kstep+1
    const unsigned short* bbase = W2r + ((size_t)khalf * C + col) * 8;
    us8 bcur0 = *(const us8*)(bbase);
    us8 bcur1 = *(const us8*)(bbase + 32 * 8);
    us8 bnx0  = *(const us8*)(bbase + (size_t)(2 * C * 8));
    us8 bnx1  = *(const us8*)(bbase + (size_t)(2 * C * 8) + 32 * 8);

    f32x16 acc[2][2];
#pragma unroll
    for (int ai = 0; ai < 2; ++ai)
#pragma unroll
        for (int nb = 0; nb < 2; ++nb)
#pragma unroll
            for (int r = 0; r < 16; ++r) acc[ai][nb][r] = 0.f;

    __syncthreads();   // Ash ready

    // depth-2 A pipeline: load kstep 0 fragments
    us8 a0c = *(const us8*)(Ash + (wave * 66 + col) * 72 + khalf * 8);
    us8 a1c = *(const us8*)(Ash + (wave * 66 + col + 32) * 72 + khalf * 8);

#pragma unroll
    for (int kstep = 0; kstep < 36; ++kstep) {
        us8 bn0, bn1;
        if (kstep + 2 < 36) {
            const unsigned short* bp = bbase + (size_t)(kstep + 2) * (2 * C * 8);
            bn0 = *(const us8*)(bp);
            bn1 = *(const us8*)(bp + 32 * 8);
        }
        // A prefetch for kstep+1 (issued before this kstep's MFMA cluster)
        us8 a0n, a1n;
        if (kstep + 1 < 36) {
            const int k1 = kstep + 1;
            const int c1 = k1 >> 2, ks1 = k1 & 3;
            const int ii1 = c1 / 3, jj1 = c1 - ii1 * 3;
            const int pb1 = (wave + ii1) * 66 + jj1;
            const int ko1 = ks1 * 16 + khalf * 8;
            a0n = *(const us8*)(Ash + (pb1 + col) * 72 + ko1);
            a1n = *(const us8*)(Ash + (pb1 + col + 32) * 72 + ko1);
        }
        bf16x8 a0 = __builtin_bit_cast(bf16x8, a0c);
        bf16x8 a1 = __builtin_bit_cast(bf16x8, a1c);
        bf16x8 v0 = __builtin_bit_cast(bf16x8, bcur0);
        bf16x8 v1 = __builtin_bit_cast(bf16x8, bcur1);
        __builtin_amdgcn_s_setprio(1);
        acc[0][0] = __builtin_amdgcn_mfma_f32_32x32x16_bf16(a0, v0, acc[0][0], 0, 0, 0);
        acc[0][1] = __builtin_amdgcn_mfma_f32_32x32x16_bf16(a0, v1, acc[0][1], 0, 0, 0);
        acc[1][0] = __builtin_amdgcn_mfma_f32_32x32x16_bf16(a1, v0, acc[1][0], 0, 0, 0);
        acc[1][1] = __builtin_amdgcn_mfma_f32_32x32x16_bf16(a1, v1, acc[1][1], 0, 0, 0);
        __builtin_amdgcn_s_setprio(0);
        bcur0 = bnx0; bcur1 = bnx1;
        bnx0 = bn0; bnx1 = bn1;
        a0c = a0n; a1c = a1n;
    }

#pragma unroll
    for (int nb = 0; nb < 2; ++nb) {
        const int n = nb * 32 + col;
        const float bias = b2[n];
#pragma unroll
        for (int ai = 0; ai < 2; ++ai) {
#pragma unroll
            for (int r = 0; r < 16; ++r) {
                int m = mrow_base + ai * 32 + (r & 3) + ((r >> 2) << 3) + (khalf << 2);
                int h = h0 + (m >> 6), w = w0 + (m & 63);
                float val = fmaxf(acc[ai][nb][r] + bias, 0.f);
                h2[(((size_t)b * HW + h) * HW + w) * C + n] = fbf(val);
            }
        }
    }
}

// --------- conv3 + NLM: depth-2 A+B prefetch, DPP epilogue reduction -----------
__global__ __launch_bounds__(512, 3) void conv3_mfma_kernel(
    const float* __restrict__ x, const unsigned short* __restrict__ h2,
    const unsigned short* __restrict__ Bg, const float* __restrict__ b3,
    float* __restrict__ y)
{
    __shared__ unsigned short Ash[396 * 72];
    __shared__ float Xsh[16 * 77];
    __shared__ float red[8][64];

    const int t = threadIdx.x;
    const int lane = t & 63;
    const int wave = t >> 6;
    const int b   = blockIdx.z;
    const int ho0 = blockIdx.y * 4;
    const int wo0 = blockIdx.x * 64;

    const int col   = lane & 31;
    const int khalf = lane >> 5;
    const int rsel      = wave >> 1;
    const int nbase     = (wave & 1) * 96;

    f32x16 acc[2][3];
#pragma unroll
    for (int mi = 0; mi < 2; ++mi)
#pragma unroll
        for (int ni = 0; ni < 3; ++ni)
#pragma unroll
            for (int r = 0; r < 16; ++r) acc[mi][ni][r] = 0.f;

#pragma unroll
    for (int it = 0; it < 7; ++it) {
        int li = it * 512 + t;
        if (li < 396 * 8) {
            int p = li >> 3, g = li & 7;
            int row = p / 66, cl = p - row * 66;
            int ww = wo0 + 5 + cl; ww = ww < 255 ? ww : 255;
            size_t src = (((size_t)b * HW + (ho0 + 5 + row)) * HW + ww) * C + g * 8;
            *(uint4*)(Ash + p * 72 + g * 8) = *(const uint4*)(h2 + src);
        }
    }
    {
        const float* __restrict__ xplane = x + ((size_t)b << 16);
#pragma unroll
        for (int it = 0; it < 3; ++it) {
            int li = it * 512 + t;
            if (li < 16 * 76) {
                int rr = li / 76, cc = li - rr * 76;
                int ww = wo0 + cc; ww = ww < 255 ? ww : 255;
                Xsh[rr * 77 + cc] = xplane[(ho0 + rr) * HW + ww];
            }
        }
    }

    // depth-2 B pipeline: bcur = kstep, bnx = kstep+1
    const unsigned short* bbase = Bg + ((size_t)khalf * NPAD + nbase + col) * 8;
    us8 bcur0 = *(const us8*)(bbase);
    us8 bcur1 = *(const us8*)(bbase + 32 * 8);
    us8 bcur2 = *(const us8*)(bbase + 64 * 8);
    us8 bnx0  = *(const us8*)(bbase + (size_t)(2 * NPAD * 8));
    us8 bnx1  = *(const us8*)(bbase + (size_t)(2 * NPAD * 8) + 32 * 8);
    us8 bnx2  = *(const us8*)(bbase + (size_t)(2 * NPAD * 8) + 64 * 8);

    __syncthreads();

    // depth-2 A pipeline: load kstep 0 fragments
    us8 a0c = *(const us8*)(Ash + (rsel * 66 + col) * 72 + khalf * 8);
    us8 a1c = *(const us8*)(Ash + (rsel * 66 + col + 32) * 72 + khalf * 8);

#pragma unroll
    for (int kstep = 0; kstep < 36; ++kstep) {
        us8 bn0, bn1, bn2;
        if (kstep + 2 < 36) {
            const unsigned short* bp = bbase + (size_t)(kstep + 2) * (2 * NPAD * 8);
            bn0 = *(const us8*)(bp);
            bn1 = *(const us8*)(bp + 32 * 8);
            bn2 = *(const us8*)(bp + 64 * 8);
        }
        // A prefetch for kstep+1 (issued before this kstep's MFMA cluster)
        us8 a0n, a1n;
        if (kstep + 1 < 36) {
            const int k1 = kstep + 1;
            const int c1 = k1 >> 2, ks1 = k1 & 3;
            const int ii1 = c1 / 3, jj1 = c1 - ii1 * 3;
            const int pb1 = (rsel + ii1) * 66 + jj1;
            const int ko1 = ks1 * 16 + khalf * 8;
            a0n = *(const us8*)(Ash + (pb1 + col) * 72 + ko1);
            a1n = *(const us8*)(Ash + (pb1 + col + 32) * 72 + ko1);
        }
        bf16x8 a0 = __builtin_bit_cast(bf16x8, a0c);
        bf16x8 a1 = __builtin_bit_cast(bf16x8, a1c);
        bf16x8 v0 = __builtin_bit_cast(bf16x8, bcur0);
        bf16x8 v1 = __builtin_bit_cast(bf16x8, bcur1);
        bf16x8 v2 = __builtin_bit_cast(bf16x8, bcur2);
        __builtin_amdgcn_s_setprio(1);
        acc[0][0] = __builtin_amdgcn_mfma_f32_32x32x16_bf16(a0, v0, acc[0][0], 0, 0, 0);
        acc[0][1] = __builtin_amdgcn_mfma_f32_32x32x16_bf16(a0, v1, acc[0][1], 0, 0, 0);
        acc[0][2] = __builtin_amdgcn_mfma_f32_32x32x16_bf16(a0, v2, acc[0][2], 0, 0, 0);
        acc[1][0] = __builtin_amdgcn_mfma_f32_32x32x16_bf16(a1, v0, acc[1][0], 0, 0, 0);
        acc[1][1] = __builtin_amdgcn_mfma_f32_32x32x16_bf16(a1, v1, acc[1][1], 0, 0, 0);
        acc[1][2] = __builtin_amdgcn_mfma_f32_32x32x16_bf16(a1, v2, acc[1][2], 0, 0, 0);
        __builtin_amdgcn_s_setprio(0);
        bcur0 = bnx0; bcur1 = bnx1; bcur2 = bnx2;
        bnx0 = bn0; bnx1 = bn1; bnx2 = bn2;
        a0c = a0n; a1c = a1n;
    }

    int   qv[3], uo[3], vo[3];
    float b3v[3];
#pragma unroll
    for (int ni = 0; ni < 3; ++ni) {
        int q = nbase + ni * 32 + col;
        qv[ni] = q;
        int u = q / 13;
        uo[ni] = u;
        vo[ni] = q - u * 13;
        b3v[ni] = (q < 169) ? b3[q] : 0.f;
    }

    // ---- fused NLM epilogue: vectorized Xsh reads + DPP butterfly reduce ----
#pragma unroll
    for (int mi = 0; mi < 2; ++mi)
#pragma unroll
        for (int j = 0; j < 4; ++j) {
            const int m0 = mi * 32 + 8 * j + (khalf << 2);
            f32x4 xv0 = *(const f32x4*)&Xsh[(rsel + uo[0]) * 77 + m0 + vo[0]];
            f32x4 xv1 = *(const f32x4*)&Xsh[(rsel + uo[1]) * 77 + m0 + vo[1]];
            f32x4 xv2 = *(const f32x4*)&Xsh[(rsel + uo[2]) * 77 + m0 + vo[2]];
#pragma unroll
            for (int q = 0; q < 4; ++q) {
                const int r = j * 4 + q;
                const int mrow = m0 + q;
                float p = 0.f;
                if ((wo0 + mrow) < HO) {
                    if (qv[0] < 169) p += (acc[mi][0][r] + b3v[0]) * xv0[q];
                    if (qv[1] < 169) p += (acc[mi][1][r] + b3v[1]) * xv1[q];
                    if (qv[2] < 169) p += (acc[mi][2][r] + b3v[2]) * xv2[q];
                }
                p = dpp_add<0xB1>(p);    // xor 1 (quad_perm [1,0,3,2])
                p = dpp_add<0x4E>(p);    // xor 2 (quad_perm [2,3,0,1])
                p = dpp_add<0x124>(p);   // row_ror:4
                p = dpp_add<0x128>(p);   // row_ror:8  -> every lane has its 16-row sum
                p = dpp_add<0x142>(p);   // row_bcast15 -> lanes 16-31/48-63: 32-sum
                if (col == 16) red[wave][mrow] = p;
            }
        }
    __syncthreads();

    if (t < 256) {
        int row_sel = t >> 6, m = t & 63;
        float val = red[row_sel * 2][m] + red[row_sel * 2 + 1][m];
        int wo = wo0 + m, ho = ho0 + row_sel;
        if (wo < HO)
            y[((size_t)b * HO + ho) * HO + wo] = val;
    }
}

extern "C" void kernel_launch(void* const* d_in, const int* in_sizes, int n_in,
                              void* d_out, int out_size, void* d_ws, size_t ws_size,
                              hipStream_t stream) {
    const float* x  = (const float*)d_in[0];
    const float* W1 = (const float*)d_in[1];
    const float* b1 = (const float*)d_in[2];
    const float* W2 = (const float*)d_in[3];
    const float* b2 = (const float*)d_in[4];
    const float* W3 = (const float*)d_in[5];
    const float* b3 = (const float*)d_in[6];
    float* out = (float*)d_out;

    unsigned short* h2  = (unsigned short*)d_ws;
    unsigned short* W2r = h2 + (size_t)BATCH * HW * HW * C;
    unsigned short* W3r = W2r + (size_t)36 * 2 * C * 8;

    repack_w_kernel<<<576, 256, 0, stream>>>(W2, W3, W2r, W3r);
    conv2_fused_kernel<<<dim3(4, 64, 8), 256, 0, stream>>>(x, W1, b1, W2r, b2, h2);
    conv3_mfma_kernel<<<dim3(4, 61, 8), 512, 0, stream>>>(x, h2, W3r, b3, out);
}

// Round 5
// 228.359 us; speedup vs baseline: 1.0076x; 1.0076x over previous
//
#include <hip/hip_runtime.h>

#define HW 256
#define BATCH 8
#define C 64
#define HO 244
#define NPAD 192
#define KTOT 576

typedef __bf16 bf16x8 __attribute__((ext_vector_type(8)));
typedef float f32x16 __attribute__((ext_vector_type(16)));
typedef float f32x4 __attribute__((ext_vector_type(4)));
typedef float f32x2 __attribute__((ext_vector_type(2)));
typedef unsigned short us8 __attribute__((ext_vector_type(8)));

// native RNE float->bf16 (v_cvt_pk_bf16_f32 capable)
__device__ inline unsigned short fbf(float f) {
    return __builtin_bit_cast(unsigned short, (__bf16)f);
}

__device__ inline float bf2f(unsigned short s) {
    union { unsigned int u; float f; } c;
    c.u = ((unsigned int)s) << 16;
    return c.f;
}

// 32-lane butterfly step on the VALU (no LDS pipe): v += dpp_move(v, CTRL)
template <int CTRL>
__device__ inline float dpp_add(float v) {
    int s = __builtin_bit_cast(int, v);
    int m = __builtin_amdgcn_update_dpp(s, s, CTRL, 0xF, 0xF, true);
    return v + __builtin_bit_cast(float, m);
}

// ---- merged W2+W3 repack, fragment-coalesced: [((kstep*2+khalf)*N + n)*8 + e] ----
__global__ __launch_bounds__(256) void repack_w_kernel(
    const float* __restrict__ W2, const float* __restrict__ W3,
    unsigned short* __restrict__ B2g, unsigned short* __restrict__ B3g)
{
    int idx = blockIdx.x * 256 + threadIdx.x;
    if (idx < 36 * 2 * C * 8) {
        int e = idx & 7;
        int r = idx >> 3;
        int n = r & 63;
        int s = r >> 6;
        int khalf = s & 1;
        int kstep = s >> 1;
        int chunk = kstep >> 2, ks = kstep & 3;
        int ci = ks * 16 + khalf * 8 + e;
        B2g[idx] = fbf(W2[((size_t)n * C + ci) * 9 + chunk]);
    } else {
        int j = idx - 36 * 2 * C * 8;
        if (j >= 36 * 2 * NPAD * 8) return;
        int e = j & 7;
        int r = j >> 3;
        int n = r % NPAD;
        int s = r / NPAD;
        int khalf = s & 1;
        int kstep = s >> 1;
        int chunk = kstep >> 2, ks = kstep & 3;
        int ci = ks * 16 + khalf * 8 + e;
        float v = (n < 169) ? W3[((size_t)n * C + ci) * 9 + chunk] : 0.f;
        B3g[j] = fbf(v);
    }
}

// ------- fused conv1+conv2: aligned Ash (stride 72), depth-2 A+B prefetch ------
__global__ __launch_bounds__(256, 3) void conv2_fused_kernel(
    const float* __restrict__ x, const float* __restrict__ W1,
    const float* __restrict__ b1, const unsigned short* __restrict__ W2r,
    const float* __restrict__ b2, unsigned short* __restrict__ h2)
{
    __shared__ unsigned short Ash[396 * 72];   // 57,024 B (stride 144B = 16B-aligned b128)
    __shared__ unsigned short Xsh[8 * 68];     //  1,088 B (bf16)

    const int t = threadIdx.x;
    const int lane = t & 63;
    const int wave = t >> 6;
    const int b  = blockIdx.z;
    const int h0 = blockIdx.y * 4;
    const int w0 = blockIdx.x * 64;

    const int col   = lane & 31;
    const int khalf = lane >> 5;
    const int mrow_base = wave * 64;

    // ---- stage x tile (bf16): rows h0-2..h0+5, cols w0-2..w0+65, zero OOB ----
    const float* __restrict__ xplane = x + ((size_t)b << 16);
#pragma unroll
    for (int it = 0; it < 3; ++it) {
        int li = it * 256 + t;
        if (li < 8 * 68) {
            int rr = li / 68, cc = li - rr * 68;
            int hh = h0 - 2 + rr, ww = w0 - 2 + cc;
            bool ok = (hh >= 0) && (hh < HW) && (ww >= 0) && (ww < HW);
            Xsh[li] = ok ? fbf(xplane[hh * HW + ww]) : (unsigned short)0;
        }
    }

    // this thread's 4 channels as two float2 pairs (packed-math path)
    const int g4 = t & 15;
    f32x2 w01[9], w23[9];
    f32x2 bia01, bia23;
    bia01[0] = b1[g4 * 4 + 0]; bia01[1] = b1[g4 * 4 + 1];
    bia23[0] = b1[g4 * 4 + 2]; bia23[1] = b1[g4 * 4 + 3];
#pragma unroll
    for (int q = 0; q < 9; ++q) {
        w01[q][0] = W1[(g4 * 4 + 0) * 9 + q];
        w01[q][1] = W1[(g4 * 4 + 1) * 9 + q];
        w23[q][0] = W1[(g4 * 4 + 2) * 9 + q];
        w23[q][1] = W1[(g4 * 4 + 3) * 9 + q];
    }

    __syncthreads();   // Xsh ready

    // ---- compute h1 tile (conv1 + ReLU + bf16) into Ash ----
    // unit = 6 consecutive pixels x 4 channels: one us8 LDS read per window row
#pragma unroll
    for (int it = 0; it < 5; ++it) {
        int li = it * 256 + t;                 // li & 15 == g4 (256 % 16 == 0)
        if (li < 1056) {
            int w = li >> 4;                   // 0..65
            int pr = w / 11;                   // Ash row 0..5
            int pc0 = (w - pr * 11) * 6;       // first pixel col (0,6,..,60)
            int hh = h0 - 1 + pr;
            bool okrow = (hh >= 0) && (hh < HW);
            const unsigned short* xb = Xsh + pr * 68 + pc0;

            f32x2 ac01[6], ac23[6];
#pragma unroll
            for (int k2 = 0; k2 < 6; ++k2) { ac01[k2] = bia01; ac23[k2] = bia23; }

#pragma unroll
            for (int i = 0; i < 3; ++i) {
                us8 xw = *(const us8*)(xb + i * 68);
                float xr[8];
#pragma unroll
                for (int e = 0; e < 8; ++e) xr[e] = bf2f(xw[e]);
#pragma unroll
                for (int k2 = 0; k2 < 6; ++k2)
#pragma unroll
                    for (int j = 0; j < 3; ++j) {
                        f32x2 xv2; xv2[0] = xr[k2 + j]; xv2[1] = xr[k2 + j];
                        ac01[k2] += xv2 * w01[i * 3 + j];
                        ac23[k2] += xv2 * w23[i * 3 + j];
                    }
            }

#pragma unroll
            for (int k2 = 0; k2 < 6; ++k2) {
                int ww = w0 - 1 + pc0 + k2;
                bool ok = okrow && (ww >= 0) && (ww < HW);
                unsigned short ov[4];
                if (ok) {
                    ov[0] = fbf(fmaxf(ac01[k2][0], 0.f));
                    ov[1] = fbf(fmaxf(ac01[k2][1], 0.f));
                    ov[2] = fbf(fmaxf(ac23[k2][0], 0.f));
                    ov[3] = fbf(fmaxf(ac23[k2][1], 0.f));
                } else {
                    ov[0] = 0; ov[1] = 0; ov[2] = 0; ov[3] = 0;
                }
                *(uint2*)(Ash + (pr * 66 + pc0 + k2) * 72 + g4 * 4) = *(uint2*)ov;
            }
        }
    }

    // depth-2 B pipeline: bcur = kstep, bnx = kstep+1
    const unsigned short* bbase = W2r + ((size_t)khalf * C + col) * 8;
    us8 bcur0 = *(const us8*)(bbase);
    us8 bcur1 = *(const us8*)(bbase + 32 * 8);
    us8 bnx0  = *(const us8*)(bbase + (size_t)(2 * C * 8));
    us8 bnx1  = *(const us8*)(bbase + (size_t)(2 * C * 8) + 32 * 8);

    f32x16 acc[2][2];
#pragma unroll
    for (int ai = 0; ai < 2; ++ai)
#pragma unroll
        for (int nb = 0; nb < 2; ++nb)
#pragma unroll
            for (int r = 0; r < 16; ++r) acc[ai][nb][r] = 0.f;

    __syncthreads();   // Ash ready

    // depth-2 A pipeline: load kstep 0 fragments
    us8 a0c = *(const us8*)(Ash + (wave * 66 + col) * 72 + khalf * 8);
    us8 a1c = *(const us8*)(Ash + (wave * 66 + col + 32) * 72 + khalf * 8);

#pragma unroll
    for (int kstep = 0; kstep < 36; ++kstep) {
        us8 bn0, bn1;
        if (kstep + 2 < 36) {
            const unsigned short* bp = bbase + (size_t)(kstep + 2) * (2 * C * 8);
            bn0 = *(const us8*)(bp);
            bn1 = *(const us8*)(bp + 32 * 8);
        }
        // A prefetch for kstep+1 (issued before this kstep's MFMA cluster)
        us8 a0n, a1n;
        if (kstep + 1 < 36) {
            const int k1 = kstep + 1;
            const int c1 = k1 >> 2, ks1 = k1 & 3;
            const int ii1 = c1 / 3, jj1 = c1 - ii1 * 3;
            const int pb1 = (wave + ii1) * 66 + jj1;
            const int ko1 = ks1 * 16 + khalf * 8;
            a0n = *(const us8*)(Ash + (pb1 + col) * 72 + ko1);
            a1n = *(const us8*)(Ash + (pb1 + col + 32) * 72 + ko1);
        }
        bf16x8 a0 = __builtin_bit_cast(bf16x8, a0c);
        bf16x8 a1 = __builtin_bit_cast(bf16x8, a1c);
        bf16x8 v0 = __builtin_bit_cast(bf16x8, bcur0);
        bf16x8 v1 = __builtin_bit_cast(bf16x8, bcur1);
        __builtin_amdgcn_s_setprio(1);
        acc[0][0] = __builtin_amdgcn_mfma_f32_32x32x16_bf16(a0, v0, acc[0][0], 0, 0, 0);
        acc[0][1] = __builtin_amdgcn_mfma_f32_32x32x16_bf16(a0, v1, acc[0][1], 0, 0, 0);
        acc[1][0] = __builtin_amdgcn_mfma_f32_32x32x16_bf16(a1, v0, acc[1][0], 0, 0, 0);
        acc[1][1] = __builtin_amdgcn_mfma_f32_32x32x16_bf16(a1, v1, acc[1][1], 0, 0, 0);
        __builtin_amdgcn_s_setprio(0);
        bcur0 = bnx0; bcur1 = bnx1;
        bnx0 = bn0; bnx1 = bn1;
        a0c = a0n; a1c = a1n;
    }

#pragma unroll
    for (int nb = 0; nb < 2; ++nb) {
        const int n = nb * 32 + col;
        const float bias = b2[n];
#pragma unroll
        for (int ai = 0; ai < 2; ++ai) {
#pragma unroll
            for (int r = 0; r < 16; ++r) {
                int m = mrow_base + ai * 32 + (r & 3) + ((r >> 2) << 3) + (khalf << 2);
                int h = h0 + (m >> 6), w = w0 + (m & 63);
                float val = fmaxf(acc[ai][nb][r] + bias, 0.f);
                h2[(((size_t)b * HW + h) * HW + w) * C + n] = fbf(val);
            }
        }
    }
}

// ---------------- conv3 + NLM: depth-2 B prefetch, DPP epilogue (R3 form) ------
__global__ __launch_bounds__(512, 3) void conv3_mfma_kernel(
    const float* __restrict__ x, const unsigned short* __restrict__ h2,
    const unsigned short* __restrict__ Bg, const float* __restrict__ b3,
    float* __restrict__ y)
{
    __shared__ unsigned short Ash[396 * 72];
    __shared__ float Xsh[16 * 77];
    __shared__ float red[8][64];

    const int t = threadIdx.x;
    const int lane = t & 63;
    const int wave = t >> 6;
    const int b   = blockIdx.z;
    const int ho0 = blockIdx.y * 4;
    const int wo0 = blockIdx.x * 64;

    const int col   = lane & 31;
    const int khalf = lane >> 5;
    const int rsel      = wave >> 1;
    const int nbase     = (wave & 1) * 96;

    f32x16 acc[2][3];
#pragma unroll
    for (int mi = 0; mi < 2; ++mi)
#pragma unroll
        for (int ni = 0; ni < 3; ++ni)
#pragma unroll
            for (int r = 0; r < 16; ++r) acc[mi][ni][r] = 0.f;

#pragma unroll
    for (int it = 0; it < 7; ++it) {
        int li = it * 512 + t;
        if (li < 396 * 8) {
            int p = li >> 3, g = li & 7;
            int row = p / 66, cl = p - row * 66;
            int ww = wo0 + 5 + cl; ww = ww < 255 ? ww : 255;
            size_t src = (((size_t)b * HW + (ho0 + 5 + row)) * HW + ww) * C + g * 8;
            *(uint4*)(Ash + p * 72 + g * 8) = *(const uint4*)(h2 + src);
        }
    }
    {
        const float* __restrict__ xplane = x + ((size_t)b << 16);
#pragma unroll
        for (int it = 0; it < 3; ++it) {
            int li = it * 512 + t;
            if (li < 16 * 76) {
                int rr = li / 76, cc = li - rr * 76;
                int ww = wo0 + cc; ww = ww < 255 ? ww : 255;
                Xsh[rr * 77 + cc] = xplane[(ho0 + rr) * HW + ww];
            }
        }
    }

    // depth-2 B pipeline: bcur = kstep, bnx = kstep+1
    const unsigned short* bbase = Bg + ((size_t)khalf * NPAD + nbase + col) * 8;
    us8 bcur0 = *(const us8*)(bbase);
    us8 bcur1 = *(const us8*)(bbase + 32 * 8);
    us8 bcur2 = *(const us8*)(bbase + 64 * 8);
    us8 bnx0  = *(const us8*)(bbase + (size_t)(2 * NPAD * 8));
    us8 bnx1  = *(const us8*)(bbase + (size_t)(2 * NPAD * 8) + 32 * 8);
    us8 bnx2  = *(const us8*)(bbase + (size_t)(2 * NPAD * 8) + 64 * 8);

    __syncthreads();

#pragma unroll
    for (int kstep = 0; kstep < 36; ++kstep) {
        const int chunk = kstep >> 2, ks = kstep & 3;
        const int ii = chunk / 3, jj = chunk - ii * 3;
        const int pixbase = (rsel + ii) * 66 + jj;
        us8 bn0, bn1, bn2;
        if (kstep + 2 < 36) {
            const unsigned short* bp = bbase + (size_t)(kstep + 2) * (2 * NPAD * 8);
            bn0 = *(const us8*)(bp);
            bn1 = *(const us8*)(bp + 32 * 8);
            bn2 = *(const us8*)(bp + 64 * 8);
        }
        const int koff = ks * 16 + khalf * 8;
        bf16x8 a0 = __builtin_bit_cast(bf16x8, *(const us8*)(Ash + (pixbase + col) * 72 + koff));
        bf16x8 a1 = __builtin_bit_cast(bf16x8, *(const us8*)(Ash + (pixbase + col + 32) * 72 + koff));
        bf16x8 v0 = __builtin_bit_cast(bf16x8, bcur0);
        bf16x8 v1 = __builtin_bit_cast(bf16x8, bcur1);
        bf16x8 v2 = __builtin_bit_cast(bf16x8, bcur2);
        acc[0][0] = __builtin_amdgcn_mfma_f32_32x32x16_bf16(a0, v0, acc[0][0], 0, 0, 0);
        acc[0][1] = __builtin_amdgcn_mfma_f32_32x32x16_bf16(a0, v1, acc[0][1], 0, 0, 0);
        acc[0][2] = __builtin_amdgcn_mfma_f32_32x32x16_bf16(a0, v2, acc[0][2], 0, 0, 0);
        acc[1][0] = __builtin_amdgcn_mfma_f32_32x32x16_bf16(a1, v0, acc[1][0], 0, 0, 0);
        acc[1][1] = __builtin_amdgcn_mfma_f32_32x32x16_bf16(a1, v1, acc[1][1], 0, 0, 0);
        acc[1][2] = __builtin_amdgcn_mfma_f32_32x32x16_bf16(a1, v2, acc[1][2], 0, 0, 0);
        bcur0 = bnx0; bcur1 = bnx1; bcur2 = bnx2;
        bnx0 = bn0; bnx1 = bn1; bnx2 = bn2;
    }

    int   qv[3], uo[3], vo[3];
    float b3v[3];
#pragma unroll
    for (int ni = 0; ni < 3; ++ni) {
        int q = nbase + ni * 32 + col;
        qv[ni] = q;
        int u = q / 13;
        uo[ni] = u;
        vo[ni] = q - u * 13;
        b3v[ni] = (q < 169) ? b3[q] : 0.f;
    }

    // ---- fused NLM epilogue: vectorized Xsh reads + DPP butterfly reduce ----
#pragma unroll
    for (int mi = 0; mi < 2; ++mi)
#pragma unroll
        for (int j = 0; j < 4; ++j) {
            const int m0 = mi * 32 + 8 * j + (khalf << 2);
            f32x4 xv0 = *(const f32x4*)&Xsh[(rsel + uo[0]) * 77 + m0 + vo[0]];
            f32x4 xv1 = *(const f32x4*)&Xsh[(rsel + uo[1]) * 77 + m0 + vo[1]];
            f32x4 xv2 = *(const f32x4*)&Xsh[(rsel + uo[2]) * 77 + m0 + vo[2]];
#pragma unroll
            for (int q = 0; q < 4; ++q) {
                const int r = j * 4 + q;
                const int mrow = m0 + q;
                float p = 0.f;
                if ((wo0 + mrow) < HO) {
                    if (qv[0] < 169) p += (acc[mi][0][r] + b3v[0]) * xv0[q];
                    if (qv[1] < 169) p += (acc[mi][1][r] + b3v[1]) * xv1[q];
                    if (qv[2] < 169) p += (acc[mi][2][r] + b3v[2]) * xv2[q];
                }
                p = dpp_add<0xB1>(p);    // xor 1 (quad_perm [1,0,3,2])
                p = dpp_add<0x4E>(p);    // xor 2 (quad_perm [2,3,0,1])
                p = dpp_add<0x124>(p);   // row_ror:4
                p = dpp_add<0x128>(p);   // row_ror:8  -> every lane has its 16-row sum
                p = dpp_add<0x142>(p);   // row_bcast15 -> lanes 16-31/48-63: 32-sum
                if (col == 16) red[wave][mrow] = p;
            }
        }
    __syncthreads();

    if (t < 256) {
        int row_sel = t >> 6, m = t & 63;
        float val = red[row_sel * 2][m] + red[row_sel * 2 + 1][m];
        int wo = wo0 + m, ho = ho0 + row_sel;
        if (wo < HO)
            y[((size_t)b * HO + ho) * HO + wo] = val;
    }
}

extern "C" void kernel_launch(void* const* d_in, const int* in_sizes, int n_in,
                              void* d_out, int out_size, void* d_ws, size_t ws_size,
                              hipStream_t stream) {
    const float* x  = (const float*)d_in[0];
    const float* W1 = (const float*)d_in[1];
    const float* b1 = (const float*)d_in[2];
    const float* W2 = (const float*)d_in[3];
    const float* b2 = (const float*)d_in[4];
    const float* W3 = (const float*)d_in[5];
    const float* b3 = (const float*)d_in[6];
    float* out = (float*)d_out;

    unsigned short* h2  = (unsigned short*)d_ws;
    unsigned short* W2r = h2 + (size_t)BATCH * HW * HW * C;
    unsigned short* W3r = W2r + (size_t)36 * 2 * C * 8;

    repack_w_kernel<<<576, 256, 0, stream>>>(W2, W3, W2r, W3r);
    conv2_fused_kernel<<<dim3(4, 64, 8), 256, 0, stream>>>(x, W1, b1, W2r, b2, h2);
    conv3_mfma_kernel<<<dim3(4, 61, 8), 512, 0, stream>>>(x, h2, W3r, b3, out);
}

// Round 6
// 222.790 us; speedup vs baseline: 1.0328x; 1.0250x over previous
//
#include <hip/hip_runtime.h>

#define HW 256
#define BATCH 8
#define C 64
#define HO 244
#define NPAD 192
#define KTOT 576

typedef __bf16 bf16x8 __attribute__((ext_vector_type(8)));
typedef float f32x16 __attribute__((ext_vector_type(16)));
typedef float f32x4 __attribute__((ext_vector_type(4)));
typedef float f32x2 __attribute__((ext_vector_type(2)));
typedef unsigned short us8 __attribute__((ext_vector_type(8)));

// native RNE float->bf16 (v_cvt_pk_bf16_f32 capable)
__device__ inline unsigned short fbf(float f) {
    return __builtin_bit_cast(unsigned short, (__bf16)f);
}

__device__ inline float bf2f(unsigned short s) {
    union { unsigned int u; float f; } c;
    c.u = ((unsigned int)s) << 16;
    return c.f;
}

// 32-lane butterfly step on the VALU (no LDS pipe): v += dpp_move(v, CTRL)
template <int CTRL>
__device__ inline float dpp_add(float v) {
    int s = __builtin_bit_cast(int, v);
    int m = __builtin_amdgcn_update_dpp(s, s, CTRL, 0xF, 0xF, true);
    return v + __builtin_bit_cast(float, m);
}

// ---- merged W2+W3 repack, fragment-coalesced: [((kstep*2+khalf)*N + n)*8 + e] ----
__global__ __launch_bounds__(256) void repack_w_kernel(
    const float* __restrict__ W2, const float* __restrict__ W3,
    unsigned short* __restrict__ B2g, unsigned short* __restrict__ B3g)
{
    int idx = blockIdx.x * 256 + threadIdx.x;
    if (idx < 36 * 2 * C * 8) {
        int e = idx & 7;
        int r = idx >> 3;
        int n = r & 63;
        int s = r >> 6;
        int khalf = s & 1;
        int kstep = s >> 1;
        int chunk = kstep >> 2, ks = kstep & 3;
        int ci = ks * 16 + khalf * 8 + e;
        B2g[idx] = fbf(W2[((size_t)n * C + ci) * 9 + chunk]);
    } else {
        int j = idx - 36 * 2 * C * 8;
        if (j >= 36 * 2 * NPAD * 8) return;
        int e = j & 7;
        int r = j >> 3;
        int n = r % NPAD;
        int s = r / NPAD;
        int khalf = s & 1;
        int kstep = s >> 1;
        int chunk = kstep >> 2, ks = kstep & 3;
        int ci = ks * 16 + khalf * 8 + e;
        float v = (n < 169) ? W3[((size_t)n * C + ci) * 9 + chunk] : 0.f;
        B3g[j] = fbf(v);
    }
}

// -- fused conv1+conv2: stride-64 XOR-swizzled Ash (3 blocks/CU, aligned b128) --
__global__ __launch_bounds__(256, 3) void conv2_fused_kernel(
    const float* __restrict__ x, const float* __restrict__ W1,
    const float* __restrict__ b1, const unsigned short* __restrict__ W2r,
    const float* __restrict__ b2, unsigned short* __restrict__ h2)
{
    __shared__ unsigned short Ash[396 * 64];   // 50,688 B; swizzle: off ^= (row&7)<<3
    __shared__ unsigned short Xsh[8 * 68];     //  1,088 B (bf16)

    const int t = threadIdx.x;
    const int lane = t & 63;
    const int wave = t >> 6;
    const int b  = blockIdx.z;
    const int h0 = blockIdx.y * 4;
    const int w0 = blockIdx.x * 64;

    const int col   = lane & 31;
    const int khalf = lane >> 5;
    const int mrow_base = wave * 64;

    // ---- stage x tile (bf16): rows h0-2..h0+5, cols w0-2..w0+65, zero OOB ----
    const float* __restrict__ xplane = x + ((size_t)b << 16);
#pragma unroll
    for (int it = 0; it < 3; ++it) {
        int li = it * 256 + t;
        if (li < 8 * 68) {
            int rr = li / 68, cc = li - rr * 68;
            int hh = h0 - 2 + rr, ww = w0 - 2 + cc;
            bool ok = (hh >= 0) && (hh < HW) && (ww >= 0) && (ww < HW);
            Xsh[li] = ok ? fbf(xplane[hh * HW + ww]) : (unsigned short)0;
        }
    }

    // this thread's 4 channels as two float2 pairs (packed-math path)
    const int g4 = t & 15;
    f32x2 w01[9], w23[9];
    f32x2 bia01, bia23;
    bia01[0] = b1[g4 * 4 + 0]; bia01[1] = b1[g4 * 4 + 1];
    bia23[0] = b1[g4 * 4 + 2]; bia23[1] = b1[g4 * 4 + 3];
#pragma unroll
    for (int q = 0; q < 9; ++q) {
        w01[q][0] = W1[(g4 * 4 + 0) * 9 + q];
        w01[q][1] = W1[(g4 * 4 + 1) * 9 + q];
        w23[q][0] = W1[(g4 * 4 + 2) * 9 + q];
        w23[q][1] = W1[(g4 * 4 + 3) * 9 + q];
    }

    __syncthreads();   // Xsh ready

    // ---- compute h1 tile (conv1 + ReLU + bf16) into Ash (swizzled write) ----
    // unit = 6 consecutive pixels x 4 channels: one us8 LDS read per window row
#pragma unroll
    for (int it = 0; it < 5; ++it) {
        int li = it * 256 + t;                 // li & 15 == g4 (256 % 16 == 0)
        if (li < 1056) {
            int w = li >> 4;                   // 0..65
            int pr = w / 11;                   // Ash row 0..5
            int pc0 = (w - pr * 11) * 6;       // first pixel col (0,6,..,60)
            int hh = h0 - 1 + pr;
            bool okrow = (hh >= 0) && (hh < HW);
            const unsigned short* xb = Xsh + pr * 68 + pc0;

            f32x2 ac01[6], ac23[6];
#pragma unroll
            for (int k2 = 0; k2 < 6; ++k2) { ac01[k2] = bia01; ac23[k2] = bia23; }

#pragma unroll
            for (int i = 0; i < 3; ++i) {
                us8 xw = *(const us8*)(xb + i * 68);
                float xr[8];
#pragma unroll
                for (int e = 0; e < 8; ++e) xr[e] = bf2f(xw[e]);
#pragma unroll
                for (int k2 = 0; k2 < 6; ++k2)
#pragma unroll
                    for (int j = 0; j < 3; ++j) {
                        f32x2 xv2; xv2[0] = xr[k2 + j]; xv2[1] = xr[k2 + j];
                        ac01[k2] += xv2 * w01[i * 3 + j];
                        ac23[k2] += xv2 * w23[i * 3 + j];
                    }
            }

#pragma unroll
            for (int k2 = 0; k2 < 6; ++k2) {
                int ww = w0 - 1 + pc0 + k2;
                bool ok = okrow && (ww >= 0) && (ww < HW);
                unsigned short ov[4];
                if (ok) {
                    ov[0] = fbf(fmaxf(ac01[k2][0], 0.f));
                    ov[1] = fbf(fmaxf(ac01[k2][1], 0.f));
                    ov[2] = fbf(fmaxf(ac23[k2][0], 0.f));
                    ov[3] = fbf(fmaxf(ac23[k2][1], 0.f));
                } else {
                    ov[0] = 0; ov[1] = 0; ov[2] = 0; ov[3] = 0;
                }
                int row = pr * 66 + pc0 + k2;
                int coff = (g4 * 4) ^ ((row & 7) << 3);   // 8B write inside 16B unit
                *(uint2*)(Ash + row * 64 + coff) = *(uint2*)ov;
            }
        }
    }

    // depth-2 B pipeline: bcur = kstep, bnx = kstep+1
    const unsigned short* bbase = W2r + ((size_t)khalf * C + col) * 8;
    us8 bcur0 = *(const us8*)(bbase);
    us8 bcur1 = *(const us8*)(bbase + 32 * 8);
    us8 bnx0  = *(const us8*)(bbase + (size_t)(2 * C * 8));
    us8 bnx1  = *(const us8*)(bbase + (size_t)(2 * C * 8) + 32 * 8);

    f32x16 acc[2][2];
#pragma unroll
    for (int ai = 0; ai < 2; ++ai)
#pragma unroll
        for (int nb = 0; nb < 2; ++nb)
#pragma unroll
            for (int r = 0; r < 16; ++r) acc[ai][nb][r] = 0.f;

    __syncthreads();   // Ash ready

    // depth-2 A pipeline: load kstep 0 fragments (swizzled read)
    us8 a0c, a1c;
    {
        int r0 = wave * 66 + col, r1 = r0 + 32;      // (r1&7)==(r0&7)
        int sw = (r0 & 7) << 3;
        a0c = *(const us8*)(Ash + r0 * 64 + ((khalf * 8) ^ sw));
        a1c = *(const us8*)(Ash + r1 * 64 + ((khalf * 8) ^ sw));
    }

#pragma unroll
    for (int kstep = 0; kstep < 36; ++kstep) {
        us8 bn0, bn1;
        if (kstep + 2 < 36) {
            const unsigned short* bp = bbase + (size_t)(kstep + 2) * (2 * C * 8);
            bn0 = *(const us8*)(bp);
            bn1 = *(const us8*)(bp + 32 * 8);
        }
        // A prefetch for kstep+1 (issued before this kstep's MFMA cluster)
        us8 a0n, a1n;
        if (kstep + 1 < 36) {
            const int k1 = kstep + 1;
            const int c1 = k1 >> 2, ks1 = k1 & 3;
            const int ii1 = c1 / 3, jj1 = c1 - ii1 * 3;
            const int ko1 = ks1 * 16 + khalf * 8;
            int r0 = (wave + ii1) * 66 + jj1 + col, r1 = r0 + 32;
            int sw = (r0 & 7) << 3;
            a0n = *(const us8*)(Ash + r0 * 64 + (ko1 ^ sw));
            a1n = *(const us8*)(Ash + r1 * 64 + (ko1 ^ sw));
        }
        bf16x8 a0 = __builtin_bit_cast(bf16x8, a0c);
        bf16x8 a1 = __builtin_bit_cast(bf16x8, a1c);
        bf16x8 v0 = __builtin_bit_cast(bf16x8, bcur0);
        bf16x8 v1 = __builtin_bit_cast(bf16x8, bcur1);
        __builtin_amdgcn_s_setprio(1);
        acc[0][0] = __builtin_amdgcn_mfma_f32_32x32x16_bf16(a0, v0, acc[0][0], 0, 0, 0);
        acc[0][1] = __builtin_amdgcn_mfma_f32_32x32x16_bf16(a0, v1, acc[0][1], 0, 0, 0);
        acc[1][0] = __builtin_amdgcn_mfma_f32_32x32x16_bf16(a1, v0, acc[1][0], 0, 0, 0);
        acc[1][1] = __builtin_amdgcn_mfma_f32_32x32x16_bf16(a1, v1, acc[1][1], 0, 0, 0);
        __builtin_amdgcn_s_setprio(0);
        bcur0 = bnx0; bcur1 = bnx1;
        bnx0 = bn0; bnx1 = bn1;
        a0c = a0n; a1c = a1n;
    }

#pragma unroll
    for (int nb = 0; nb < 2; ++nb) {
        const int n = nb * 32 + col;
        const float bias = b2[n];
#pragma unroll
        for (int ai = 0; ai < 2; ++ai) {
#pragma unroll
            for (int r = 0; r < 16; ++r) {
                int m = mrow_base + ai * 32 + (r & 3) + ((r >> 2) << 3) + (khalf << 2);
                int h = h0 + (m >> 6), w = w0 + (m & 63);
                float val = fmaxf(acc[ai][nb][r] + bias, 0.f);
                h2[(((size_t)b * HW + h) * HW + w) * C + n] = fbf(val);
            }
        }
    }
}

// ---------------- conv3 + NLM: depth-2 B prefetch, DPP epilogue (R3 form) ------
__global__ __launch_bounds__(512, 3) void conv3_mfma_kernel(
    const float* __restrict__ x, const unsigned short* __restrict__ h2,
    const unsigned short* __restrict__ Bg, const float* __restrict__ b3,
    float* __restrict__ y)
{
    __shared__ unsigned short Ash[396 * 72];
    __shared__ float Xsh[16 * 77];
    __shared__ float red[8][64];

    const int t = threadIdx.x;
    const int lane = t & 63;
    const int wave = t >> 6;
    const int b   = blockIdx.z;
    const int ho0 = blockIdx.y * 4;
    const int wo0 = blockIdx.x * 64;

    const int col   = lane & 31;
    const int khalf = lane >> 5;
    const int rsel      = wave >> 1;
    const int nbase     = (wave & 1) * 96;

    f32x16 acc[2][3];
#pragma unroll
    for (int mi = 0; mi < 2; ++mi)
#pragma unroll
        for (int ni = 0; ni < 3; ++ni)
#pragma unroll
            for (int r = 0; r < 16; ++r) acc[mi][ni][r] = 0.f;

#pragma unroll
    for (int it = 0; it < 7; ++it) {
        int li = it * 512 + t;
        if (li < 396 * 8) {
            int p = li >> 3, g = li & 7;
            int row = p / 66, cl = p - row * 66;
            int ww = wo0 + 5 + cl; ww = ww < 255 ? ww : 255;
            size_t src = (((size_t)b * HW + (ho0 + 5 + row)) * HW + ww) * C + g * 8;
            *(uint4*)(Ash + p * 72 + g * 8) = *(const uint4*)(h2 + src);
        }
    }
    {
        const float* __restrict__ xplane = x + ((size_t)b << 16);
#pragma unroll
        for (int it = 0; it < 3; ++it) {
            int li = it * 512 + t;
            if (li < 16 * 76) {
                int rr = li / 76, cc = li - rr * 76;
                int ww = wo0 + cc; ww = ww < 255 ? ww : 255;
                Xsh[rr * 77 + cc] = xplane[(ho0 + rr) * HW + ww];
            }
        }
    }

    // depth-2 B pipeline: bcur = kstep, bnx = kstep+1
    const unsigned short* bbase = Bg + ((size_t)khalf * NPAD + nbase + col) * 8;
    us8 bcur0 = *(const us8*)(bbase);
    us8 bcur1 = *(const us8*)(bbase + 32 * 8);
    us8 bcur2 = *(const us8*)(bbase + 64 * 8);
    us8 bnx0  = *(const us8*)(bbase + (size_t)(2 * NPAD * 8));
    us8 bnx1  = *(const us8*)(bbase + (size_t)(2 * NPAD * 8) + 32 * 8);
    us8 bnx2  = *(const us8*)(bbase + (size_t)(2 * NPAD * 8) + 64 * 8);

    __syncthreads();

#pragma unroll
    for (int kstep = 0; kstep < 36; ++kstep) {
        const int chunk = kstep >> 2, ks = kstep & 3;
        const int ii = chunk / 3, jj = chunk - ii * 3;
        const int pixbase = (rsel + ii) * 66 + jj;
        us8 bn0, bn1, bn2;
        if (kstep + 2 < 36) {
            const unsigned short* bp = bbase + (size_t)(kstep + 2) * (2 * NPAD * 8);
            bn0 = *(const us8*)(bp);
            bn1 = *(const us8*)(bp + 32 * 8);
            bn2 = *(const us8*)(bp + 64 * 8);
        }
        const int koff = ks * 16 + khalf * 8;
        bf16x8 a0 = __builtin_bit_cast(bf16x8, *(const us8*)(Ash + (pixbase + col) * 72 + koff));
        bf16x8 a1 = __builtin_bit_cast(bf16x8, *(const us8*)(Ash + (pixbase + col + 32) * 72 + koff));
        bf16x8 v0 = __builtin_bit_cast(bf16x8, bcur0);
        bf16x8 v1 = __builtin_bit_cast(bf16x8, bcur1);
        bf16x8 v2 = __builtin_bit_cast(bf16x8, bcur2);
        acc[0][0] = __builtin_amdgcn_mfma_f32_32x32x16_bf16(a0, v0, acc[0][0], 0, 0, 0);
        acc[0][1] = __builtin_amdgcn_mfma_f32_32x32x16_bf16(a0, v1, acc[0][1], 0, 0, 0);
        acc[0][2] = __builtin_amdgcn_mfma_f32_32x32x16_bf16(a0, v2, acc[0][2], 0, 0, 0);
        acc[1][0] = __builtin_amdgcn_mfma_f32_32x32x16_bf16(a1, v0, acc[1][0], 0, 0, 0);
        acc[1][1] = __builtin_amdgcn_mfma_f32_32x32x16_bf16(a1, v1, acc[1][1], 0, 0, 0);
        acc[1][2] = __builtin_amdgcn_mfma_f32_32x32x16_bf16(a1, v2, acc[1][2], 0, 0, 0);
        bcur0 = bnx0; bcur1 = bnx1; bcur2 = bnx2;
        bnx0 = bn0; bnx1 = bn1; bnx2 = bn2;
    }

    int   qv[3], uo[3], vo[3];
    float b3v[3];
#pragma unroll
    for (int ni = 0; ni < 3; ++ni) {
        int q = nbase + ni * 32 + col;
        qv[ni] = q;
        int u = q / 13;
        uo[ni] = u;
        vo[ni] = q - u * 13;
        b3v[ni] = (q < 169) ? b3[q] : 0.f;
    }

    // ---- fused NLM epilogue: vectorized Xsh reads + DPP butterfly reduce ----
#pragma unroll
    for (int mi = 0; mi < 2; ++mi)
#pragma unroll
        for (int j = 0; j < 4; ++j) {
            const int m0 = mi * 32 + 8 * j + (khalf << 2);
            f32x4 xv0 = *(const f32x4*)&Xsh[(rsel + uo[0]) * 77 + m0 + vo[0]];
            f32x4 xv1 = *(const f32x4*)&Xsh[(rsel + uo[1]) * 77 + m0 + vo[1]];
            f32x4 xv2 = *(const f32x4*)&Xsh[(rsel + uo[2]) * 77 + m0 + vo[2]];
#pragma unroll
            for (int q = 0; q < 4; ++q) {
                const int r = j * 4 + q;
                const int mrow = m0 + q;
                float p = 0.f;
                if ((wo0 + mrow) < HO) {
                    if (qv[0] < 169) p += (acc[mi][0][r] + b3v[0]) * xv0[q];
                    if (qv[1] < 169) p += (acc[mi][1][r] + b3v[1]) * xv1[q];
                    if (qv[2] < 169) p += (acc[mi][2][r] + b3v[2]) * xv2[q];
                }
                p = dpp_add<0xB1>(p);    // xor 1 (quad_perm [1,0,3,2])
                p = dpp_add<0x4E>(p);    // xor 2 (quad_perm [2,3,0,1])
                p = dpp_add<0x124>(p);   // row_ror:4
                p = dpp_add<0x128>(p);   // row_ror:8  -> every lane has its 16-row sum
                p = dpp_add<0x142>(p);   // row_bcast15 -> lanes 16-31/48-63: 32-sum
                if (col == 16) red[wave][mrow] = p;
            }
        }
    __syncthreads();

    if (t < 256) {
        int row_sel = t >> 6, m = t & 63;
        float val = red[row_sel * 2][m] + red[row_sel * 2 + 1][m];
        int wo = wo0 + m, ho = ho0 + row_sel;
        if (wo < HO)
            y[((size_t)b * HO + ho) * HO + wo] = val;
    }
}

extern "C" void kernel_launch(void* const* d_in, const int* in_sizes, int n_in,
                              void* d_out, int out_size, void* d_ws, size_t ws_size,
                              hipStream_t stream) {
    const float* x  = (const float*)d_in[0];
    const float* W1 = (const float*)d_in[1];
    const float* b1 = (const float*)d_in[2];
    const float* W2 = (const float*)d_in[3];
    const float* b2 = (const float*)d_in[4];
    const float* W3 = (const float*)d_in[5];
    const float* b3 = (const float*)d_in[6];
    float* out = (float*)d_out;

    unsigned short* h2  = (unsigned short*)d_ws;
    unsigned short* W2r = h2 + (size_t)BATCH * HW * HW * C;
    unsigned short* W3r = W2r + (size_t)36 * 2 * C * 8;

    repack_w_kernel<<<576, 256, 0, stream>>>(W2, W3, W2r, W3r);
    conv2_fused_kernel<<<dim3(4, 64, 8), 256, 0, stream>>>(x, W1, b1, W2r, b2, h2);
    conv3_mfma_kernel<<<dim3(4, 61, 8), 512, 0, stream>>>(x, h2, W3r, b3, out);
}